// Round 11
// baseline (93.360 us; speedup 1.0000x reference)
//
#include <hip/hip_runtime.h>
#include <hip/hip_bf16.h>

// DiffAlphaSplitModel: VOCAB=64, H=64, HALF=32, B=256, L=2048.
//  DUAL-SPACE per-position recurrence (lane = vocab v):
//    d = gf[t_p] (v_readlane);  gf -= d * (c_p*G[:,t_p]);  r += d * (c_p*h[t_p][:])
//  ROUND-11: single lgkm domain + in-order DS pipelining.
//   - seq staged to LDS packed u16 (no SMEM/VMEM in loop; r10's lgkmcnt(0)
//     drain came from out-of-order s_loads sharing lgkmcnt with ds_read).
//   - per body: TOUCH (wait for last body's raw reads, already arrived) ->
//     prescale -> convert tokens (readfirstlane+SALU unpack) -> issue next
//     ds_tok + ds_raw -> sched_barrier -> chain (ZERO memory waits).
//   - r accumulated directly from prescaled h-columns (no histogram).
//  s-chain (wave 0, c=1: no prescale) and e-chain (wave 1) separate waves.
//
// ws layout (floats):
//   [0     ..  4095] compact k [2][64][32]
//   [4096  ..  8191] compact h [2][64][32]
//   [16384 .. 24575] Gram [2][64][64]
//   [24576 .. 40959] rbuf [256][64]

#define L_SEQ 2048
#define NPOS  2047

__device__ __forceinline__ float rdlane(float v, int l) {
    return __int_as_float(__builtin_amdgcn_readlane(__float_as_int(v), l));
}

// ---------------- Kernel A: per-vocab tables -------------------------------
__global__ void build_tables(const float* __restrict__ embed,
                             const float* __restrict__ w1, const float* __restrict__ b1,
                             const float* __restrict__ w2, const float* __restrict__ b2,
                             const float* __restrict__ ln_g, const float* __restrict__ ln_b,
                             const float* __restrict__ ws, const float* __restrict__ bs,
                             const float* __restrict__ we, const float* __restrict__ be,
                             float* __restrict__ tabs) {
    const int v = blockIdx.x;
    const int t = threadIdx.x;        // 0..63
    __shared__ float sh_h[64];
    __shared__ float sh_a[128];
    __shared__ float sh_x[64];

    sh_h[t] = embed[v * 64 + t];
    __syncthreads();

    float acc0 = b1[t], acc1 = b1[t + 64];
    #pragma unroll 8
    for (int k = 0; k < 64; ++k) {
        const float hv = sh_h[k];
        acc0 += hv * w1[k * 128 + t];
        acc1 += hv * w1[k * 128 + t + 64];
    }
    sh_a[t]      = fmaxf(acc0, 0.f);
    sh_a[t + 64] = fmaxf(acc1, 0.f);
    __syncthreads();

    float x = sh_h[t] + b2[t];
    #pragma unroll 8
    for (int k = 0; k < 128; ++k) x += sh_a[k] * w2[k * 64 + t];

    float mu = x;
    for (int m = 1; m <= 32; m <<= 1) mu += __shfl_xor(mu, m);
    mu *= (1.f / 64.f);
    const float dx = x - mu;
    float var = dx * dx;
    for (int m = 1; m <= 32; m <<= 1) var += __shfl_xor(var, m);
    var *= (1.f / 64.f);
    const float hln = dx * rsqrtf(var + 1e-5f) * ln_g[t] + ln_b[t];
    sh_x[t] = hln;
    __syncthreads();

    const int j   = t & 31;
    const int mem = t >> 5;
    const float* W  = mem ? we : ws;
    const float* Bv = mem ? be : bs;
    float p = Bv[j];
    #pragma unroll 8
    for (int k = 0; k < 64; ++k) p += sh_x[k] * W[k * 32 + j];

    float nn = p * p;
    for (int m = 1; m <= 16; m <<= 1) nn += __shfl_xor(nn, m);
    const float kn = p / fmaxf(sqrtf(nn), 1e-12f);

    tabs[(mem * 64 + v) * 32 + j]        = kn;   // normalized key
    tabs[4096 + (mem * 64 + v) * 32 + j] = p;    // raw projection
}

// ---------------- Kernel A2: Gram tables -----------------------------------
__global__ void gram_kernel(const float* __restrict__ tabs, float* __restrict__ gout) {
    const int v  = blockIdx.x;
    const int tt = threadIdx.x;          // 0..127
    const int m  = tt >> 6, w = tt & 63;
    __shared__ float kv[64];
    if (tt < 64) kv[tt] = tabs[((tt >> 5) * 64 + v) * 32 + (tt & 31)];
    __syncthreads();
    const float* kw  = &tabs[(m * 64 + w) * 32];
    const float* kvm = &kv[m * 32];
    float acc = 0.f;
    #pragma unroll 8
    for (int j = 0; j < 32; ++j) acc += kvm[j] * kw[j];
    gout[m * 4096 + v * 64 + w] = acc;
}

// ======== per-body macros (static indexing, named banks) ====================
// 16 packed words (uint4 x4) -> TV; block KK tokens = words [16*KK .. 16*KK+15]
#define LOADTOKS(KK, TV) do {                                                 \
    const uint4* p_ = (const uint4*)&seq16[(KK) << 4];                        \
    TV[0] = p_[0]; TV[1] = p_[1]; TV[2] = p_[2]; TV[3] = p_[3]; } while (0)

// unpack TV -> 32 uniform tokens in TS (readfirstlane + SALU bfe)
#define CONVERT(TV, TS) do {                                                  \
    _Pragma("unroll")                                                         \
    for (int i2 = 0; i2 < 4; ++i2) {                                          \
      const unsigned wx_ = (unsigned)__builtin_amdgcn_readfirstlane((int)TV[i2].x); \
      const unsigned wy_ = (unsigned)__builtin_amdgcn_readfirstlane((int)TV[i2].y); \
      const unsigned wz_ = (unsigned)__builtin_amdgcn_readfirstlane((int)TV[i2].z); \
      const unsigned ww_ = (unsigned)__builtin_amdgcn_readfirstlane((int)TV[i2].w); \
      TS[8*i2+0] = (int)(wx_ & 0xffffu); TS[8*i2+1] = (int)(wx_ >> 16);       \
      TS[8*i2+2] = (int)(wy_ & 0xffffu); TS[8*i2+3] = (int)(wy_ >> 16);       \
      TS[8*i2+4] = (int)(wz_ & 0xffffu); TS[8*i2+5] = (int)(wz_ >> 16);       \
      TS[8*i2+6] = (int)(ww_ & 0xffffu); TS[8*i2+7] = (int)(ww_ >> 16);       \
    } } while (0)

// issue 64 ds_read: G-column (2-way, free) + h-column (broadcast pairs, free)
#define LOADRAW(TS, CG, HC) do {                                              \
    _Pragma("unroll")                                                         \
    for (int j = 0; j < 32; ++j) {                                            \
      CG[j] = gt [rowV + TS[j]];                                              \
      HC[j] = hsh[rowH + (TS[j] << 5)];                                       \
    } } while (0)

// force the lgkm wait HERE (in-order DS: last raw read newest)
#define TOUCH(CG, HC) asm volatile("" :: "v"(CG[31]), "v"(HC[31]))

// e-wave: fold c_p into both columns (s-wave: c=1, skip)
#define PRESCALE(KB, CG, HC) do {                                             \
    if (mF) { const float cb_ = (float)(32 * (KB) + 1) * invL;                \
      _Pragma("unroll")                                                       \
      for (int j = 0; j < 32; ++j) {                                          \
        const float c_ = cb_ + (float)j * invL;                               \
        CG[j] *= c_; HC[j] *= c_;                                             \
      } } } while (0)

// serial chain: readlane + fmac(gf); r-fmac off-chain. j = JTOP..0
#define CHAIN(TS, CG, HC, JTOP) do {                                          \
    _Pragma("unroll")                                                         \
    for (int j = (JTOP); j >= 0; --j) {                                       \
      const float d_ = rdlane(gf, TS[j]);                                     \
      gf = fmaf(-d_, CG[j], gf);                                              \
      r  = fmaf( d_, HC[j], r);                                               \
    } } while (0)

// ---------------- Kernel B: dual-space scan, in-order-DS pipelined ---------
// grid 256 (batch), block 128 = 2 waves. wave 0: s-chain, wave 1: e-chain.
__global__ void __launch_bounds__(128, 1) scan_kernel(const int* __restrict__ seq,
                                                      const float* __restrict__ tabs,
                                                      float* __restrict__ rbuf) {
    const int b    = blockIdx.x;
    const int tid  = threadIdx.x;        // 0..127
    const int m    = tid >> 6;           // wave id == chain id
    const int lane = tid & 63;           // vocab id v
    const int q    = lane & 31;

    __shared__ float    gt  [2 * 64 * 65];   // Gram rows padded to 65
    __shared__ float    hsh [2 * 64 * 32];   // h tables [m][v][j]
    __shared__ unsigned seq16[1024];         // packed u16 tokens (2/word)

    // ---- stage (one-time) ----
    for (int i = tid; i < 8192; i += 128) {
        const int mm = i >> 12, v = (i >> 6) & 63, ww = i & 63;
        gt[mm * 4160 + v * 65 + ww] = tabs[16384 + i];
    }
    for (int i = tid; i < 1024; i += 128)
        ((float4*)hsh)[i] = ((const float4*)(tabs + 4096))[i];
    {
        const int4* s4 = (const int4*)(seq + b * L_SEQ);
        for (int i = tid; i < 512; i += 128) {
            const int4 vv = s4[i];
            seq16[2*i]     = (unsigned)vv.x | ((unsigned)vv.y << 16);
            seq16[2*i + 1] = (unsigned)vv.z | ((unsigned)vv.w << 16);
        }
    }
    __syncthreads();

    const int   rowV = m * 4160 + lane * 65;      // G row base (elements)
    const int   rowH = m * 2048 + q;              // h col base (elements)
    const float invL = 1.0f / (float)L_SEQ;
    const bool  mF   = (m != 0);

    // init: u = k_tokL  =>  gf_v = G[v][tokL]   (token 2047 = word 1023 hi)
    const int tokL = (int)((unsigned)__builtin_amdgcn_readfirstlane(
                              (int)seq16[1023]) >> 16);
    float gf = gt[rowV + tokL];
    float r  = 0.f;

    // banks: even blocks -> E, odd blocks -> O
    uint4 tvE[4], tvO[4];
    int   tsE[32], tsO[32];
    float cgE[32], hcE[32], cgO[32], hcO[32];

    // ---- prologue ----
    LOADTOKS(63, tvO);
    LOADTOKS(62, tvE);
    CONVERT(tvO, tsO);              // waits both token reads (in-order)
    LOADRAW(tsO, cgO, hcO);         // raw(63)
    TOUCH(cgO, hcO);                // one exposed wait (prologue only)
    PRESCALE(63, cgO, hcO);
    CONVERT(tvE, tsE);              // 62 (already arrived)
    LOADTOKS(61, tvO);
    LOADRAW(tsE, cgE, hcE);         // raw(62)
    __builtin_amdgcn_sched_barrier(0);
    CHAIN(tsO, cgO, hcO, 30);       // block 63: positions 2046..2016

    // body 62
    TOUCH(cgE, hcE);
    PRESCALE(62, cgE, hcE);
    CONVERT(tvO, tsO);              // 61
    LOADTOKS(60, tvE);
    LOADRAW(tsO, cgO, hcO);         // raw(61)
    __builtin_amdgcn_sched_barrier(0);
    CHAIN(tsE, cgE, hcE, 31);       // block 62

    // ---- main loop: k2 = 61, 59, ..., 1  (bodies k2 [odd,O] and k2-1 [even,E])
    for (int k2 = 61; k2 >= 1; k2 -= 2) {
        if (__all(fabsf(gf) < 1e-6f)) break;   // residual-based exit (per wave)

        // body k2 (odd, O banks)
        TOUCH(cgO, hcO);
        PRESCALE(k2, cgO, hcO);
        CONVERT(tvE, tsE);                       // tokens k2-1
        { const int kk = (k2 >= 2) ? k2 - 2 : 0; LOADTOKS(kk, tvO); }
        LOADRAW(tsE, cgE, hcE);                  // raw(k2-1)
        __builtin_amdgcn_sched_barrier(0);
        CHAIN(tsO, cgO, hcO, 31);

        // body k2-1 (even, E banks)
        TOUCH(cgE, hcE);
        PRESCALE(k2 - 1, cgE, hcE);
        if (k2 > 1) {
            CONVERT(tvO, tsO);                   // tokens k2-2
            { const int kk = (k2 >= 3) ? k2 - 3 : 0; LOADTOKS(kk, tvE); }
            LOADRAW(tsO, cgO, hcO);              // raw(k2-2)
        }
        __builtin_amdgcn_sched_barrier(0);
        CHAIN(tsE, cgE, hcE, 31);
    }

    if (lane < 32)
        rbuf[b * 64 + m * 32 + q] = r;   // [rs | re] = concat order
}

// ---------------- Kernel C: output projection ------------------------------
__global__ void out_kernel(const float* __restrict__ rbuf,
                           const float* __restrict__ wrp, const float* __restrict__ brp,
                           const float* __restrict__ wout, const float* __restrict__ bout,
                           float* __restrict__ out) {
    const int b = blockIdx.x;
    const int t = threadIdx.x;
    __shared__ float rsh[64];
    __shared__ float ysh[64];

    rsh[t] = rbuf[b * 64 + t];
    __syncthreads();

    float y = brp[t];
    #pragma unroll 8
    for (int k = 0; k < 64; ++k) y += rsh[k] * wrp[k * 64 + t];
    ysh[t] = y;
    __syncthreads();

    float o = bout[t];
    #pragma unroll 8
    for (int k = 0; k < 64; ++k) o += ysh[k] * wout[k * 64 + t];
    out[b * 64 + t] = o;
}

// ---------------- launch ----------------------------------------------------
extern "C" void kernel_launch(void* const* d_in, const int* in_sizes, int n_in,
                              void* d_out, int out_size, void* d_ws, size_t ws_size,
                              hipStream_t stream) {
    const int*   seq   = (const int*)  d_in[0];
    const float* embed = (const float*)d_in[1];
    const float* w1    = (const float*)d_in[2];
    const float* b1    = (const float*)d_in[3];
    const float* w2    = (const float*)d_in[4];
    const float* b2    = (const float*)d_in[5];
    const float* ln_g  = (const float*)d_in[6];
    const float* ln_b  = (const float*)d_in[7];
    const float* ws    = (const float*)d_in[8];
    const float* bs    = (const float*)d_in[9];
    const float* we    = (const float*)d_in[10];
    const float* be    = (const float*)d_in[11];
    const float* wrp   = (const float*)d_in[12];
    const float* brp   = (const float*)d_in[13];
    const float* wout  = (const float*)d_in[14];
    const float* bout  = (const float*)d_in[15];

    float* tabs = (float*)d_ws;              // tables + gram
    float* gout = tabs + 16384;              // gram [2][64][64]
    float* rbuf = tabs + 24576;              // r vectors [256][64]

    build_tables<<<64, 64, 0, stream>>>(embed, w1, b1, w2, b2, ln_g, ln_b,
                                        ws, bs, we, be, tabs);
    gram_kernel<<<64, 128, 0, stream>>>(tabs, gout);
    scan_kernel<<<256, 128, 0, stream>>>(seq, tabs, rbuf);
    out_kernel<<<256, 64, 0, stream>>>(rbuf, wrp, brp, wout, bout, (float*)d_out);
}

// Round 12
// 92.408 us; speedup vs baseline: 1.0103x; 1.0103x over previous
//
#include <hip/hip_runtime.h>
#include <hip/hip_bf16.h>

// DiffAlphaSplitModel: VOCAB=64, H=64, HALF=32, B=256, L=2048.
//  DUAL-SPACE per-position recurrence (lane = vocab v):
//    d_p = gf[t_p];  e_p = c_p d_p;  gf -= e_p G[:,t_p];  r += e_p h[t_p][:]
//  ROUND-12: QUAD-BATCHED chain. r7/r9/r11 all measured ~85-95 cy/pos with
//  the same serial core (readlane->SGPR->fmac); backed-out readlane round
//  trip ~76 cy. Fix: process 4 positions per serial step:
//   - 4 independent readlanes from the SAME pre-quad gf (one L_r, batched)
//   - in-register triangular correction with gamma_{b,a} = G[t_b][t_a],
//     obtained via readlane(cg_a, t_b) on already-loaded G-columns in the
//     BATCH phase (SGPR-read hazard hidden there)
//   - solve runs in uniform VGPRs (e = c*d, c uniform VGPR); <=1 SGPR/op
//   - gf/r updates: 4 fmacs each (VGPR x VGPR)
//  Position 2047 neutralized via c=0 in the top quad of the first block.
//  s-chain (c=1: step=0, ctop=1) and e-chain in separate waves (block=128).
//
// ws layout (floats):
//   [0     ..  4095] compact k [2][64][32]
//   [4096  ..  8191] compact h [2][64][32]
//   [16384 .. 24575] Gram [2][64][64]
//   [24576 .. 40959] rbuf [256][64]

#define L_SEQ 2048
#define NPOS  2047

__device__ __forceinline__ float rdlane(float v, int l) {
    return __int_as_float(__builtin_amdgcn_readlane(__float_as_int(v), l));
}

// ---------------- Kernel A: per-vocab tables -------------------------------
__global__ void build_tables(const float* __restrict__ embed,
                             const float* __restrict__ w1, const float* __restrict__ b1,
                             const float* __restrict__ w2, const float* __restrict__ b2,
                             const float* __restrict__ ln_g, const float* __restrict__ ln_b,
                             const float* __restrict__ ws, const float* __restrict__ bs,
                             const float* __restrict__ we, const float* __restrict__ be,
                             float* __restrict__ tabs) {
    const int v = blockIdx.x;
    const int t = threadIdx.x;        // 0..63
    __shared__ float sh_h[64];
    __shared__ float sh_a[128];
    __shared__ float sh_x[64];

    sh_h[t] = embed[v * 64 + t];
    __syncthreads();

    float acc0 = b1[t], acc1 = b1[t + 64];
    #pragma unroll 8
    for (int k = 0; k < 64; ++k) {
        const float hv = sh_h[k];
        acc0 += hv * w1[k * 128 + t];
        acc1 += hv * w1[k * 128 + t + 64];
    }
    sh_a[t]      = fmaxf(acc0, 0.f);
    sh_a[t + 64] = fmaxf(acc1, 0.f);
    __syncthreads();

    float x = sh_h[t] + b2[t];
    #pragma unroll 8
    for (int k = 0; k < 128; ++k) x += sh_a[k] * w2[k * 64 + t];

    float mu = x;
    for (int m = 1; m <= 32; m <<= 1) mu += __shfl_xor(mu, m);
    mu *= (1.f / 64.f);
    const float dx = x - mu;
    float var = dx * dx;
    for (int m = 1; m <= 32; m <<= 1) var += __shfl_xor(var, m);
    var *= (1.f / 64.f);
    const float hln = dx * rsqrtf(var + 1e-5f) * ln_g[t] + ln_b[t];
    sh_x[t] = hln;
    __syncthreads();

    const int j   = t & 31;
    const int mem = t >> 5;
    const float* W  = mem ? we : ws;
    const float* Bv = mem ? be : bs;
    float p = Bv[j];
    #pragma unroll 8
    for (int k = 0; k < 64; ++k) p += sh_x[k] * W[k * 32 + j];

    float nn = p * p;
    for (int m = 1; m <= 16; m <<= 1) nn += __shfl_xor(nn, m);
    const float kn = p / fmaxf(sqrtf(nn), 1e-12f);

    tabs[(mem * 64 + v) * 32 + j]        = kn;   // normalized key
    tabs[4096 + (mem * 64 + v) * 32 + j] = p;    // raw projection
}

// ---------------- Kernel A2: Gram tables -----------------------------------
__global__ void gram_kernel(const float* __restrict__ tabs, float* __restrict__ gout) {
    const int v  = blockIdx.x;
    const int tt = threadIdx.x;          // 0..127
    const int m  = tt >> 6, w = tt & 63;
    __shared__ float kv[64];
    if (tt < 64) kv[tt] = tabs[((tt >> 5) * 64 + v) * 32 + (tt & 31)];
    __syncthreads();
    const float* kw  = &tabs[(m * 64 + w) * 32];
    const float* kvm = &kv[m * 32];
    float acc = 0.f;
    #pragma unroll 8
    for (int j = 0; j < 32; ++j) acc += kvm[j] * kw[j];
    gout[m * 4096 + v * 64 + w] = acc;
}

// ---------------- Kernel B: dual-space scan, quad-batched chain ------------
// grid 256 (batch), block 128 = 2 waves. wave 0: s-chain, wave 1: e-chain.
// lane (0..63) = vocab id v for gf.
__global__ void __launch_bounds__(128, 1) scan_kernel(const int* __restrict__ seq,
                                                      const float* __restrict__ tabs,
                                                      float* __restrict__ rbuf) {
    const int b    = blockIdx.x;
    const int tid  = threadIdx.x;        // 0..127
    const int m    = tid >> 6;           // wave id == chain id
    const int lane = tid & 63;           // vocab id v
    const int q    = lane & 31;

    __shared__ float    gt  [2 * 64 * 65];   // Gram rows padded to 65
    __shared__ float    hsh [2 * 64 * 32];   // h tables [m][v][j]
    __shared__ unsigned seq16[1024];         // packed u16 tokens (2/word)

    // ---- stage (one-time) ----
    for (int i = tid; i < 8192; i += 128) {
        const int mm = i >> 12, v = (i >> 6) & 63, ww = i & 63;
        gt[mm * 4160 + v * 65 + ww] = tabs[16384 + i];
    }
    for (int i = tid; i < 1024; i += 128)
        ((float4*)hsh)[i] = ((const float4*)(tabs + 4096))[i];
    {
        const int4* s4 = (const int4*)(seq + b * L_SEQ);
        for (int i = tid; i < 512; i += 128) {
            const int4 vv = s4[i];
            seq16[2*i]     = (unsigned)vv.x | ((unsigned)vv.y << 16);
            seq16[2*i + 1] = (unsigned)vv.z | ((unsigned)vv.w << 16);
        }
    }
    __syncthreads();

    const int   rowV = m * 4160 + lane * 65;      // G row base (elements)
    const int   rowH = m * 2048 + q;              // h col base (elements)
    const float invL = 1.0f / (float)L_SEQ;
    const bool  mF   = (m != 0);
    const float step = mF ? invL : 0.0f;          // c decrement per position

    // init: u = k_tokL  =>  gf_v = G[v][tokL]   (token 2047 = word 1023 hi)
    const int tokL = (int)((unsigned)__builtin_amdgcn_readfirstlane(
                              (int)seq16[1023]) >> 16);
    float gf = gt[rowV + tokL];
    float r  = 0.f;

    for (int pb = 2016; pb >= 0; pb -= 32) {
        if (__all(fabsf(gf) < 1e-6f)) break;       // residual-based exit

        // ---- batch: tokens -> SGPR, cg/hc loads, gamma readlanes ----
        int ts[32];
        #pragma unroll
        for (int w = 0; w < 16; ++w) {
            const unsigned pw = (unsigned)__builtin_amdgcn_readfirstlane(
                                    (int)seq16[(pb >> 1) + w]);
            ts[2*w]     = (int)(pw & 0xffffu);
            ts[2*w + 1] = (int)(pw >> 16);
        }
        float cgb[32], hcb[32];
        #pragma unroll
        for (int i = 0; i < 32; ++i) {
            cgb[i] = gt [rowV + ts[i]];                 // G[:,t_i] (per-lane)
            hcb[i] = hsh[rowH + (ts[i] << 5)];          // h[t_i][q]
        }
        // gammas: G[t_b][t_a] = readlane(cg_a, t_b); batched (hazard hidden)
        float G32[8], G31[8], G30[8], G21[8], G20[8], G10[8];
        #pragma unroll
        for (int k = 0; k < 8; ++k) {
            const int i0 = 4*k, i1 = i0+1, i2 = i0+2, i3 = i0+3;
            G32[k] = rdlane(cgb[i3], ts[i2]);
            G31[k] = rdlane(cgb[i3], ts[i1]);
            G30[k] = rdlane(cgb[i3], ts[i0]);
            G21[k] = rdlane(cgb[i2], ts[i1]);
            G20[k] = rdlane(cgb[i2], ts[i0]);
            G10[k] = rdlane(cgb[i1], ts[i0]);
        }
        const float ctop = mF ? (float)(pb + 32) * invL : 1.0f;
        const bool  topBlk = (pb == 2016);          // contains position 2047

        __builtin_amdgcn_sched_barrier(0);

        // ---- chain: 8 quads, backward (k=7 first) ----
        float cRun = ctop;
        #pragma unroll
        for (int k = 7; k >= 0; --k) {
            const int i0 = 4*k, i1 = i0+1, i2 = i0+2, i3 = i0+3;
            float c3 = cRun;
            if (k == 7) c3 = topBlk ? 0.f : c3;     // neutralize pos 2047
            const float c2 = cRun - step;
            const float c1 = c2 - step;
            const float c0 = c1 - step;
            cRun = c0 - step;

            const float a3 = rdlane(gf, ts[i3]);
            const float a2 = rdlane(gf, ts[i2]);
            const float a1 = rdlane(gf, ts[i1]);
            const float a0 = rdlane(gf, ts[i0]);

            const float e3 = c3 * a3;                       // d3 = a3
            const float d2 = a2 - G32[k] * e3;
            const float e2 = c2 * d2;
            const float t1 = fmaf(G21[k], e2, G31[k] * e3);
            const float d1 = a1 - t1;
            const float e1 = c1 * d1;
            const float t0 = fmaf(G10[k], e1,
                             fmaf(G20[k], e2, G30[k] * e3));
            const float d0 = a0 - t0;
            const float e0 = c0 * d0;

            gf = fmaf(-e3, cgb[i3], gf);
            gf = fmaf(-e2, cgb[i2], gf);
            gf = fmaf(-e1, cgb[i1], gf);
            gf = fmaf(-e0, cgb[i0], gf);

            r  = fmaf(e3, hcb[i3], r);
            r  = fmaf(e2, hcb[i2], r);
            r  = fmaf(e1, hcb[i1], r);
            r  = fmaf(e0, hcb[i0], r);
        }
    }

    if (lane < 32)
        rbuf[b * 64 + m * 32 + q] = r;   // [rs | re] = concat order
}

// ---------------- Kernel C: output projection ------------------------------
__global__ void out_kernel(const float* __restrict__ rbuf,
                           const float* __restrict__ wrp, const float* __restrict__ brp,
                           const float* __restrict__ wout, const float* __restrict__ bout,
                           float* __restrict__ out) {
    const int b = blockIdx.x;
    const int t = threadIdx.x;
    __shared__ float rsh[64];
    __shared__ float ysh[64];

    rsh[t] = rbuf[b * 64 + t];
    __syncthreads();

    float y = brp[t];
    #pragma unroll 8
    for (int k = 0; k < 64; ++k) y += rsh[k] * wrp[k * 64 + t];
    ysh[t] = y;
    __syncthreads();

    float o = bout[t];
    #pragma unroll 8
    for (int k = 0; k < 64; ++k) o += ysh[k] * wout[k * 64 + t];
    out[b * 64 + t] = o;
}

// ---------------- launch ----------------------------------------------------
extern "C" void kernel_launch(void* const* d_in, const int* in_sizes, int n_in,
                              void* d_out, int out_size, void* d_ws, size_t ws_size,
                              hipStream_t stream) {
    const int*   seq   = (const int*)  d_in[0];
    const float* embed = (const float*)d_in[1];
    const float* w1    = (const float*)d_in[2];
    const float* b1    = (const float*)d_in[3];
    const float* w2    = (const float*)d_in[4];
    const float* b2    = (const float*)d_in[5];
    const float* ln_g  = (const float*)d_in[6];
    const float* ln_b  = (const float*)d_in[7];
    const float* ws    = (const float*)d_in[8];
    const float* bs    = (const float*)d_in[9];
    const float* we    = (const float*)d_in[10];
    const float* be    = (const float*)d_in[11];
    const float* wrp   = (const float*)d_in[12];
    const float* brp   = (const float*)d_in[13];
    const float* wout  = (const float*)d_in[14];
    const float* bout  = (const float*)d_in[15];

    float* tabs = (float*)d_ws;              // tables + gram
    float* gout = tabs + 16384;              // gram [2][64][64]
    float* rbuf = tabs + 24576;              // r vectors [256][64]

    build_tables<<<64, 64, 0, stream>>>(embed, w1, b1, w2, b2, ln_g, ln_b,
                                        ws, bs, we, be, tabs);
    gram_kernel<<<64, 128, 0, stream>>>(tabs, gout);
    scan_kernel<<<256, 128, 0, stream>>>(seq, tabs, rbuf);
    out_kernel<<<256, 64, 0, stream>>>(rbuf, wrp, brp, wout, bout, (float*)d_out);
}